// Round 1
// baseline (203.918 us; speedup 1.0000x reference)
//
#include <hip/hip_runtime.h>
#include <cstdint>
#include <cstddef>

// Problem constants
#define NCLUS 64
#define DIM   128
#define BATCH 512            // K of the Gram reduction
#define QCOLS 8192           // NCLUS*DIM
#define NPAIR 2016           // 64*63/2

typedef __bf16 bf16_t;
typedef __bf16 bf16x8 __attribute__((ext_vector_type(8)));
typedef float  f32x4  __attribute__((ext_vector_type(4)));

__device__ __forceinline__ unsigned short f2bf(float x) {
  unsigned int u = __float_as_uint(x);
  u += 0x7fffu + ((u >> 16) & 1u);   // round-to-nearest-even
  return (unsigned short)(u >> 16);
}

__device__ __forceinline__ void ld_lds16(const void* g, void* l) {
  __builtin_amdgcn_global_load_lds(
      (__attribute__((address_space(1))) void*)g,
      (__attribute__((address_space(3))) void*)l, 16, 0, 0);
}

// ---------------------------------------------------------------------------
// Kernel 1: softmax over D=128, q^2 -> bf16, write TRANSPOSED layout
// q2t[t][x=c*128+d][b]  (row stride 512, K-contiguous for the Gram kernel),
// plus the self-sim dot accumulated into accum[0].
// Block: (bq in 0..15, c in 0..63), 256 threads = 4 waves, 32 b's per block.
// ---------------------------------------------------------------------------
__global__ __launch_bounds__(256) void softmax_q2_kernel(
    const float* __restrict__ emb, unsigned short* __restrict__ q2t,
    float* __restrict__ accum) {
  __shared__ unsigned short T[2][32][DIM];   // [tensor][b_local][d] 16 KB
  __shared__ float red[4];
  const int c  = blockIdx.y;
  const int bq = blockIdx.x;
  const int tid = threadIdx.x;
  const int w = tid >> 6, lane = tid & 63;

  float dot = 0.f;
  for (int r = 0; r < 8; ++r) {
    const int bl = w * 8 + r;          // 0..31
    const int b  = bq * 32 + bl;       // 0..511
    float qa0 = 0.f, qa1 = 0.f;
#pragma unroll
    for (int t = 0; t < 2; ++t) {
      const float2* rp =
          (const float2*)(emb + ((size_t)(t * BATCH + b) * QCOLS + (size_t)c * DIM));
      float2 v = rp[lane];             // d = 2*lane, 2*lane+1
      float mx = fmaxf(v.x, v.y);
#pragma unroll
      for (int off = 32; off > 0; off >>= 1) mx = fmaxf(mx, __shfl_xor(mx, off));
      float e0 = __expf(v.x - mx), e1 = __expf(v.y - mx);
      float s = e0 + e1;
#pragma unroll
      for (int off = 32; off > 0; off >>= 1) s += __shfl_xor(s, off);
      float inv = 1.0f / s;
      float q0 = e0 * inv, q1 = e1 * inv;
      if (t == 0) { qa0 = q0; qa1 = q1; }
      else        { dot += qa0 * q0 + qa1 * q1; }
      unsigned int pk =
          (unsigned int)f2bf(q0 * q0) | ((unsigned int)f2bf(q1 * q1) << 16);
      *(unsigned int*)&T[t][bl][2 * lane] = pk;   // 4B packed, conflict-free
    }
  }
  __syncthreads();

  // coalesced transposed write-out: per tensor 128 d-rows x 32 b (64 B each)
#pragma unroll
  for (int t = 0; t < 2; ++t) {
#pragma unroll
    for (int i = 0; i < 2; ++i) {
      int ch = i * 256 + tid;          // 0..511 chunks of 16 B
      int d = ch >> 2, b8 = ch & 3;    // 8 consecutive b per chunk
      uint4 o;
      o.x = (unsigned int)T[t][b8 * 8 + 0][d] | ((unsigned int)T[t][b8 * 8 + 1][d] << 16);
      o.y = (unsigned int)T[t][b8 * 8 + 2][d] | ((unsigned int)T[t][b8 * 8 + 3][d] << 16);
      o.z = (unsigned int)T[t][b8 * 8 + 4][d] | ((unsigned int)T[t][b8 * 8 + 5][d] << 16);
      o.w = (unsigned int)T[t][b8 * 8 + 6][d] | ((unsigned int)T[t][b8 * 8 + 7][d] << 16);
      size_t off = (size_t)t * ((size_t)QCOLS * BATCH) +
                   (size_t)(c * DIM + d) * BATCH + (size_t)bq * 32 + b8 * 8;
      *(uint4*)(q2t + off) = o;
    }
  }

  // self-sim dot reduction: wave shuffle -> LDS -> one atomic per block
#pragma unroll
  for (int off = 32; off > 0; off >>= 1) dot += __shfl_xor(dot, off);
  if (lane == 0) red[w] = dot;
  __syncthreads();
  if (tid == 0) atomicAdd(accum + 0, red[0] + red[1] + red[2] + red[3]);
}

// ---------------------------------------------------------------------------
// Kernel 2: Gram tile (J,I), J<I.  G_tile[m][n] = sum_k A[m][k]*B[n][k],
// A row m = Q2T[J*128+m][:], B row n = Q2T[I*128+n][:], K=512, BK=32.
// 128x128 tile, 4 waves (2x2), each wave 4x4 of 16x16x32 bf16 MFMA.
// Epilogue: sum(sqrt(acc)) over all elements -> atomicAdd(accum[1]).
// ---------------------------------------------------------------------------
__global__ __launch_bounds__(256) void gram_sqrt_kernel(
    const bf16_t* __restrict__ q2t, float* __restrict__ accum) {
  __shared__ bf16_t Asm[128 * 32];   // [m][k] row = 64 B, k-chunks XOR-swizzled
  __shared__ bf16_t Bsm[128 * 32];
  __shared__ float red[4];

  const int p = blockIdx.x;          // 0..2015
  const int t = blockIdx.y;          // tensor
  int I = (int)((1.0f + sqrtf(1.0f + 8.0f * (float)p)) * 0.5f);
  while (I * (I - 1) / 2 > p) --I;
  while ((I + 1) * I / 2 <= p) ++I;
  const int J = p - I * (I - 1) / 2;

  const size_t tbase = (size_t)t * ((size_t)QCOLS * BATCH);
  const bf16_t* baseA = q2t + tbase + (size_t)(J * DIM) * BATCH;
  const bf16_t* baseB = q2t + tbase + (size_t)(I * DIM) * BATCH;

  const int tid  = threadIdx.x;
  const int lane = tid & 63, w = tid >> 6;
  const int wm = w & 1, wn = w >> 1;
  const int mrow = tid >> 2;                       // 0..63 (round adds +64)
  // staging XOR swizzle: thread (tid&3) stores global k-chunk (tid&3)^(m&3)
  const int kch = (((tid & 3) ^ (mrow & 3)) * 8);  // element offset in BK=32

  f32x4 acc[4][4];
#pragma unroll
  for (int i = 0; i < 4; ++i)
#pragma unroll
    for (int j = 0; j < 4; ++j) acc[i][j] = (f32x4){0.f, 0.f, 0.f, 0.f};

  char* AsmB = (char*)Asm;
  char* BsmB = (char*)Bsm;
  const int ldsw = w * 1024;                       // wave-uniform LDS base

  const int l15 = lane & 15;
  const int sw  = (lane >> 4) ^ (lane & 3);        // reader-side unswizzle
  const bf16_t* Ap = Asm + (wm * 64 + l15) * 32 + sw * 8;
  const bf16_t* Bp = Bsm + (wn * 64 + l15) * 32 + sw * 8;

  for (int k0 = 0; k0 < BATCH; k0 += 32) {
    // stage A,B tiles: 2 rounds x 64 rows, 16 B per lane, direct-to-LDS
    ld_lds16(baseA + (size_t)mrow * BATCH + k0 + kch,        AsmB + ldsw);
    ld_lds16(baseA + (size_t)(64 + mrow) * BATCH + k0 + kch, AsmB + 4096 + ldsw);
    ld_lds16(baseB + (size_t)mrow * BATCH + k0 + kch,        BsmB + ldsw);
    ld_lds16(baseB + (size_t)(64 + mrow) * BATCH + k0 + kch, BsmB + 4096 + ldsw);
    __syncthreads();

    bf16x8 a[4], b[4];
#pragma unroll
    for (int i = 0; i < 4; ++i) {
      a[i] = *(const bf16x8*)(Ap + i * 512);   // +16 rows per frag
      b[i] = *(const bf16x8*)(Bp + i * 512);
    }
#pragma unroll
    for (int i = 0; i < 4; ++i)
#pragma unroll
      for (int j = 0; j < 4; ++j)
        acc[i][j] = __builtin_amdgcn_mfma_f32_16x16x32_bf16(a[i], b[j], acc[i][j], 0, 0, 0);
    __syncthreads();
  }

  // epilogue: sum of sqrt over the whole 128x128 tile (layout-invariant)
  float local = 0.f;
#pragma unroll
  for (int i = 0; i < 4; ++i)
#pragma unroll
    for (int j = 0; j < 4; ++j)
#pragma unroll
      for (int e = 0; e < 4; ++e) local += sqrtf(acc[i][j][e]);

#pragma unroll
  for (int off = 32; off > 0; off >>= 1) local += __shfl_xor(local, off);
  if (lane == 0) red[w] = local;
  __syncthreads();
  if (tid == 0) atomicAdd(accum + 1, red[0] + red[1] + red[2] + red[3]);
}

// ---------------------------------------------------------------------------
// Kernel 3: combine.  loss = -dot/(B*N_C) - S/((N_C^2-N_C)*sqrt(B))
// (factor 2 from J<I symmetry cancels the /2 average over the two tensors)
// ---------------------------------------------------------------------------
__global__ void finalize_kernel(const float* __restrict__ accum,
                                float* __restrict__ out) {
  const float scale = 4032.0f * 22.62741699796952f;  // (64^2-64)*sqrt(512)
  out[0] = -accum[0] / 32768.0f - accum[1] / scale;
}

extern "C" void kernel_launch(void* const* d_in, const int* in_sizes, int n_in,
                              void* d_out, int out_size, void* d_ws, size_t ws_size,
                              hipStream_t stream) {
  const float* emb = (const float*)d_in[0];
  float* out = (float*)d_out;
  float* accum = (float*)d_ws;                              // [0]=dot, [1]=S
  unsigned short* q2t = (unsigned short*)((char*)d_ws + 256);  // 2 x 8192 x 512 bf16

  hipMemsetAsync(d_ws, 0, 256, stream);                     // zero accumulators
  softmax_q2_kernel<<<dim3(16, 64), 256, 0, stream>>>(emb, q2t, accum);
  gram_sqrt_kernel<<<dim3(NPAIR, 2), 256, 0, stream>>>((const bf16_t*)q2t, accum);
  finalize_kernel<<<1, 1, 0, stream>>>(accum, out);
}

// Round 2
// 188.054 us; speedup vs baseline: 1.0844x; 1.0844x over previous
//
#include <hip/hip_runtime.h>
#include <cstdint>
#include <cstddef>

// Problem constants
#define NCLUS 64
#define DIM   128
#define BATCH 512            // K of the Gram reduction
#define QCOLS 8192           // NCLUS*DIM
#define NPAIR 2016           // 64*63/2
#define BK    64             // K-chunk per LDS stage

typedef __bf16 bf16_t;
typedef __bf16 bf16x8 __attribute__((ext_vector_type(8)));
typedef float  f32x4  __attribute__((ext_vector_type(4)));

__device__ __forceinline__ unsigned short f2bf(float x) {
  unsigned int u = __float_as_uint(x);
  u += 0x7fffu + ((u >> 16) & 1u);   // round-to-nearest-even
  return (unsigned short)(u >> 16);
}

__device__ __forceinline__ void ld_lds16(const void* g, void* l) {
  __builtin_amdgcn_global_load_lds(
      (__attribute__((address_space(1))) void*)g,
      (__attribute__((address_space(3))) void*)l, 16, 0, 0);
}

// ---------------------------------------------------------------------------
// Kernel 1: softmax over D=128, q^2 -> bf16, transposed write q2t[t][c*128+d][b].
// Block (bq, c): 32 b's x 2 tensors = 64 rows, 8 threads/row (16 d's each).
// All rows processed concurrently; shuffle chains are 3 steps (8-lane groups).
// ---------------------------------------------------------------------------
__global__ __launch_bounds__(256) void softmax_q2_kernel(
    const float* __restrict__ emb, unsigned short* __restrict__ q2t,
    float* __restrict__ accum) {
  __shared__ unsigned short T[2][32][DIM];   // [tensor][b_local][d] 16 KB
  __shared__ float red[4];
  const int c  = blockIdx.y;
  const int bq = blockIdx.x;
  const int tid = threadIdx.x;
  const int w = tid >> 6, lane = tid & 63;
  const int bl = tid >> 3;                   // 0..31
  const int part = tid & 7;                  // 0..7, d-range part*16..+16
  const int b = bq * 32 + bl;

  float qa[16];
  float dot = 0.f;
#pragma unroll
  for (int t = 0; t < 2; ++t) {
    const float4* rp = (const float4*)(emb + ((size_t)(t * BATCH + b) * QCOLS +
                                              (size_t)c * DIM + part * 16));
    float f[16];
#pragma unroll
    for (int u = 0; u < 4; ++u) {
      float4 v = rp[u];
      f[4*u] = v.x; f[4*u+1] = v.y; f[4*u+2] = v.z; f[4*u+3] = v.w;
    }
    float mx = f[0];
#pragma unroll
    for (int j = 1; j < 16; ++j) mx = fmaxf(mx, f[j]);
#pragma unroll
    for (int off = 1; off < 8; off <<= 1) mx = fmaxf(mx, __shfl_xor(mx, off));
    float s = 0.f;
#pragma unroll
    for (int j = 0; j < 16; ++j) { f[j] = __expf(f[j] - mx); s += f[j]; }
#pragma unroll
    for (int off = 1; off < 8; off <<= 1) s += __shfl_xor(s, off);
    float inv = 1.0f / s;
    uint32_t* Tu = (uint32_t*)&T[t][bl][part * 16];
#pragma unroll
    for (int j = 0; j < 16; j += 2) {
      float q0 = f[j] * inv, q1 = f[j + 1] * inv;
      if (t == 0) { qa[j] = q0; qa[j + 1] = q1; }
      else        { dot += qa[j] * q0 + qa[j + 1] * q1; }
      Tu[j >> 1] = (uint32_t)f2bf(q0 * q0) | ((uint32_t)f2bf(q1 * q1) << 16);
    }
  }
  __syncthreads();

  // coalesced transposed write-out: 16-B chunks of 8 consecutive b per d
#pragma unroll
  for (int t = 0; t < 2; ++t) {
#pragma unroll
    for (int i = 0; i < 2; ++i) {
      int ch = i * 256 + tid;          // 0..511 chunks of 16 B
      int d = ch >> 2, b8 = ch & 3;
      uint4 o;
      o.x = (uint32_t)T[t][b8 * 8 + 0][d] | ((uint32_t)T[t][b8 * 8 + 1][d] << 16);
      o.y = (uint32_t)T[t][b8 * 8 + 2][d] | ((uint32_t)T[t][b8 * 8 + 3][d] << 16);
      o.z = (uint32_t)T[t][b8 * 8 + 4][d] | ((uint32_t)T[t][b8 * 8 + 5][d] << 16);
      o.w = (uint32_t)T[t][b8 * 8 + 6][d] | ((uint32_t)T[t][b8 * 8 + 7][d] << 16);
      size_t off = (size_t)t * ((size_t)QCOLS * BATCH) +
                   (size_t)(c * DIM + d) * BATCH + (size_t)bq * 32 + b8 * 8;
      *(uint4*)(q2t + off) = o;
    }
  }

  // self-sim dot: full-wave xor reduce -> LDS -> one atomic per block
#pragma unroll
  for (int off = 1; off < 64; off <<= 1) dot += __shfl_xor(dot, off);
  if (lane == 0) red[w] = dot;
  __syncthreads();
  if (tid == 0) atomicAdd(accum + 0, red[0] + red[1] + red[2] + red[3]);
}

// ---------------------------------------------------------------------------
// Kernel 2: Gram tile (J,I), J<I, K=512, BK=64, 128x128 tile, 4 waves (2x2),
// each wave 4x4 of 16x16x32 bf16 MFMA. Pair index is remapped so each XCD
// (blockIdx%8 round-robin) works a contiguous supertile-ordered region:
// resident blocks per XCD share ~2-3 MB of panels -> L2-resident staging.
// Epilogue: sum(sqrt(acc)) (layout-invariant) -> atomicAdd(accum[1]).
// ---------------------------------------------------------------------------
__global__ __launch_bounds__(256) void gram_sqrt_kernel(
    const bf16_t* __restrict__ q2t, float* __restrict__ accum) {
  __shared__ bf16_t Asm[128 * BK];   // 16 KB, row = 128 B, chunk-XOR swizzled
  __shared__ bf16_t Bsm[128 * BK];
  __shared__ float red[4];

  // ---- pair decode: XCD partition + 8x8 supertile order ----
  int sidx = ((int)blockIdx.x & 7) * 252 + ((int)blockIdx.x >> 3);
  int q = sidx, gi = 0;
  while (q >= 64 * gi + 28) { q -= 64 * gi + 28; ++gi; }
  int I, J;
  if (q < 64 * gi) {                      // off-diagonal supertile (gi, gj)
    int gj = q >> 6, r = q & 63;
    I = gi * 8 + (r >> 3);
    J = gj * 8 + (r & 7);
  } else {                                // diagonal supertile (gi, gi)
    int dq = q - 64 * gi;
    int il = 1;
    while (il * (il + 1) / 2 <= dq) ++il;
    I = gi * 8 + il;
    J = gi * 8 + (dq - il * (il - 1) / 2);
  }
  const int t = blockIdx.y;

  const size_t tbase = (size_t)t * ((size_t)QCOLS * BATCH);
  const bf16_t* baseA = q2t + tbase + (size_t)(J * DIM) * BATCH;
  const bf16_t* baseB = q2t + tbase + (size_t)(I * DIM) * BATCH;

  const int tid  = threadIdx.x;
  const int lane = tid & 63, w = tid >> 6;
  const int wm = w & 1, wn = w >> 1;

  // staging: slot = r*256 + tid -> row = r*32 + (tid>>3), chunk-slot = tid&7,
  // content chunk = slot ^ (row&7); global element offset (per round base):
  const int rr = tid >> 3;
  const int cc = (tid & 7) ^ (rr & 7);
  const int goff = rr * BATCH + cc * 8;

  f32x4 acc[4][4];
#pragma unroll
  for (int i = 0; i < 4; ++i)
#pragma unroll
    for (int j = 0; j < 4; ++j) acc[i][j] = (f32x4){0.f, 0.f, 0.f, 0.f};

  char* AsmB = (char*)Asm;
  char* BsmB = (char*)Bsm;
  const int ldsw = w * 1024;

  // reader: row R = w?*64 + i*16 + l15; k-step s chunk = (s*4+qtr) ^ (R&7)
  const int l15 = lane & 15, qtr = lane >> 4;
  const bf16_t* Ap0 = Asm + (wm * 64 + l15) * BK + (((qtr)     ^ (l15 & 7)) * 8);
  const bf16_t* Ap1 = Asm + (wm * 64 + l15) * BK + (((4 + qtr) ^ (l15 & 7)) * 8);
  const bf16_t* Bp0 = Bsm + (wn * 64 + l15) * BK + (((qtr)     ^ (l15 & 7)) * 8);
  const bf16_t* Bp1 = Bsm + (wn * 64 + l15) * BK + (((4 + qtr) ^ (l15 & 7)) * 8);

  for (int k0 = 0; k0 < BATCH; k0 += BK) {
    const bf16_t* ga = baseA + goff + k0;
    const bf16_t* gb = baseB + goff + k0;
#pragma unroll
    for (int r = 0; r < 4; ++r) {        // 4 rounds x 32 rows per tile
      ld_lds16(ga + r * (32 * BATCH), AsmB + r * 4096 + ldsw);
      ld_lds16(gb + r * (32 * BATCH), BsmB + r * 4096 + ldsw);
    }
    __syncthreads();

    bf16x8 a[4], b[4];
    // k-step 0
#pragma unroll
    for (int i = 0; i < 4; ++i) {
      a[i] = *(const bf16x8*)(Ap0 + i * (16 * BK));
      b[i] = *(const bf16x8*)(Bp0 + i * (16 * BK));
    }
#pragma unroll
    for (int i = 0; i < 4; ++i)
#pragma unroll
      for (int j = 0; j < 4; ++j)
        acc[i][j] = __builtin_amdgcn_mfma_f32_16x16x32_bf16(a[i], b[j], acc[i][j], 0, 0, 0);
    // k-step 1
#pragma unroll
    for (int i = 0; i < 4; ++i) {
      a[i] = *(const bf16x8*)(Ap1 + i * (16 * BK));
      b[i] = *(const bf16x8*)(Bp1 + i * (16 * BK));
    }
#pragma unroll
    for (int i = 0; i < 4; ++i)
#pragma unroll
      for (int j = 0; j < 4; ++j)
        acc[i][j] = __builtin_amdgcn_mfma_f32_16x16x32_bf16(a[i], b[j], acc[i][j], 0, 0, 0);
    __syncthreads();
  }

  // epilogue: sum of sqrt over the whole 128x128 tile (layout-invariant)
  float local = 0.f;
#pragma unroll
  for (int i = 0; i < 4; ++i)
#pragma unroll
    for (int j = 0; j < 4; ++j)
#pragma unroll
      for (int e = 0; e < 4; ++e) local += sqrtf(acc[i][j][e]);

#pragma unroll
  for (int off = 32; off > 0; off >>= 1) local += __shfl_xor(local, off);
  if (lane == 0) red[w] = local;
  __syncthreads();
  if (tid == 0) atomicAdd(accum + 1, red[0] + red[1] + red[2] + red[3]);
}

// ---------------------------------------------------------------------------
// Kernel 3: combine.  loss = -dot/(B*N_C) - S/((N_C^2-N_C)*sqrt(B))
// (factor 2 from J<I symmetry cancels the /2 average over the two tensors)
// ---------------------------------------------------------------------------
__global__ void finalize_kernel(const float* __restrict__ accum,
                                float* __restrict__ out) {
  const float scale = 4032.0f * 22.62741699796952f;  // (64^2-64)*sqrt(512)
  out[0] = -accum[0] / 32768.0f - accum[1] / scale;
}

extern "C" void kernel_launch(void* const* d_in, const int* in_sizes, int n_in,
                              void* d_out, int out_size, void* d_ws, size_t ws_size,
                              hipStream_t stream) {
  const float* emb = (const float*)d_in[0];
  float* out = (float*)d_out;
  float* accum = (float*)d_ws;                                 // [0]=dot, [1]=S
  unsigned short* q2t = (unsigned short*)((char*)d_ws + 256);  // 2 x 8192 x 512 bf16

  hipMemsetAsync(d_ws, 0, 256, stream);
  softmax_q2_kernel<<<dim3(16, 64), 256, 0, stream>>>(emb, q2t, accum);
  gram_sqrt_kernel<<<dim3(NPAIR, 2), 256, 0, stream>>>((const bf16_t*)q2t, accum);
  finalize_kernel<<<1, 1, 0, stream>>>(accum, out);
}

// Round 3
// 160.504 us; speedup vs baseline: 1.2705x; 1.1717x over previous
//
#include <hip/hip_runtime.h>
#include <cstdint>
#include <cstddef>

// Problem constants
#define NCLUS 64
#define DIM   128
#define BATCH 512            // K of the Gram reduction
#define QCOLS 8192           // NCLUS*DIM
#define NPAIR 2016           // 64*63/2
#define BK    64             // K-chunk per LDS stage
#define TSTR  (QCOLS * BATCH)  // elements per tensor (4,194,304)

typedef __bf16 bf16_t;
typedef __bf16 bf16x8 __attribute__((ext_vector_type(8)));
typedef float  f32x4  __attribute__((ext_vector_type(4)));

__device__ __forceinline__ unsigned short f2bf(float x) {
  unsigned int u = __float_as_uint(x);
  u += 0x7fffu + ((u >> 16) & 1u);   // round-to-nearest-even
  return (unsigned short)(u >> 16);
}

__device__ __forceinline__ void ld_lds16(const void* g, void* l) {
  __builtin_amdgcn_global_load_lds(
      (__attribute__((address_space(1))) void*)g,
      (__attribute__((address_space(3))) void*)l, 16, 0, 0);
}

// manual sync points (asm volatile + memory clobber = full compiler fence,
// so the prefetch ld_lds can NOT be sunk below the vmcnt wait)
#define SYNC_VM8()  asm volatile("s_waitcnt vmcnt(8)\n\ts_barrier" ::: "memory")
#define SYNC_VM0()  asm volatile("s_waitcnt vmcnt(0)\n\ts_barrier" ::: "memory")
#define SYNC_LGKM() asm volatile("s_waitcnt lgkmcnt(0)\n\ts_barrier" ::: "memory")

// ---------------------------------------------------------------------------
// Kernel 1: softmax over D=128, q^2 -> bf16, transposed write q2t[t][c*128+d][b].
// Block (bq, c): 32 b's x 2 tensors, 8 threads/row. Per-block dot partial ->
// plain store (no atomic, no memset dependency).
// ---------------------------------------------------------------------------
__global__ __launch_bounds__(256) void softmax_q2_kernel(
    const float* __restrict__ emb, unsigned short* __restrict__ q2t,
    float* __restrict__ dotPart) {
  __shared__ unsigned short T[2][32][DIM];   // 16 KB
  __shared__ float red[4];
  const int c  = blockIdx.y;
  const int bq = blockIdx.x;
  const int tid = threadIdx.x;
  const int w = tid >> 6, lane = tid & 63;
  const int bl = tid >> 3;                   // 0..31
  const int part = tid & 7;                  // d-range part*16..+16
  const int b = bq * 32 + bl;

  float qa[16];
  float dot = 0.f;
#pragma unroll
  for (int t = 0; t < 2; ++t) {
    const float4* rp = (const float4*)(emb + ((size_t)(t * BATCH + b) * QCOLS +
                                              (size_t)c * DIM + part * 16));
    float f[16];
#pragma unroll
    for (int u = 0; u < 4; ++u) {
      float4 v = rp[u];
      f[4*u] = v.x; f[4*u+1] = v.y; f[4*u+2] = v.z; f[4*u+3] = v.w;
    }
    float mx = f[0];
#pragma unroll
    for (int j = 1; j < 16; ++j) mx = fmaxf(mx, f[j]);
#pragma unroll
    for (int off = 1; off < 8; off <<= 1) mx = fmaxf(mx, __shfl_xor(mx, off));
    float s = 0.f;
#pragma unroll
    for (int j = 0; j < 16; ++j) { f[j] = __expf(f[j] - mx); s += f[j]; }
#pragma unroll
    for (int off = 1; off < 8; off <<= 1) s += __shfl_xor(s, off);
    float inv = 1.0f / s;
    uint32_t* Tu = (uint32_t*)&T[t][bl][part * 16];
#pragma unroll
    for (int j = 0; j < 16; j += 2) {
      float q0 = f[j] * inv, q1 = f[j + 1] * inv;
      if (t == 0) { qa[j] = q0; qa[j + 1] = q1; }
      else        { dot += qa[j] * q0 + qa[j + 1] * q1; }
      Tu[j >> 1] = (uint32_t)f2bf(q0 * q0) | ((uint32_t)f2bf(q1 * q1) << 16);
    }
  }
  __syncthreads();

  // coalesced transposed write-out
#pragma unroll
  for (int t = 0; t < 2; ++t) {
#pragma unroll
    for (int i = 0; i < 2; ++i) {
      int ch = i * 256 + tid;          // 0..511 chunks of 16 B
      int d = ch >> 2, b8 = ch & 3;
      uint4 o;
      o.x = (uint32_t)T[t][b8 * 8 + 0][d] | ((uint32_t)T[t][b8 * 8 + 1][d] << 16);
      o.y = (uint32_t)T[t][b8 * 8 + 2][d] | ((uint32_t)T[t][b8 * 8 + 3][d] << 16);
      o.z = (uint32_t)T[t][b8 * 8 + 4][d] | ((uint32_t)T[t][b8 * 8 + 5][d] << 16);
      o.w = (uint32_t)T[t][b8 * 8 + 6][d] | ((uint32_t)T[t][b8 * 8 + 7][d] << 16);
      size_t off = (size_t)t * (size_t)TSTR +
                   (size_t)(c * DIM + d) * BATCH + (size_t)bq * 32 + b8 * 8;
      *(uint4*)(q2t + off) = o;
    }
  }

#pragma unroll
  for (int off = 1; off < 64; off <<= 1) dot += __shfl_xor(dot, off);
  if (lane == 0) red[w] = dot;
  __syncthreads();
  if (tid == 0) dotPart[blockIdx.y * 16 + blockIdx.x] = red[0] + red[1] + red[2] + red[3];
}

// ---------------------------------------------------------------------------
// Kernel 2: Gram tile (J,I), J<I, BOTH tensors per block (16 k-iters of BK=64),
// 128x128 tile, 4 waves (2x2), 16x16x32 bf16 MFMA, double-buffered LDS
// (2 x 32 KB) with one-stage-ahead global_load_lds prefetch synced by
// s_waitcnt vmcnt(8) (oldest-8 semantics). XCD supertile pair ordering.
// Per-block partial S -> plain store.
// ---------------------------------------------------------------------------
__global__ __launch_bounds__(256) void gram_sqrt_kernel(
    const bf16_t* __restrict__ q2t, float* __restrict__ Spart) {
  __shared__ bf16_t L[32768];   // 64 KB: buf(m&1) at el (m&1)*16384; A +0, B +8192

  // ---- pair decode: XCD partition + 8x8 supertile order ----
  int sidx = ((int)blockIdx.x & 7) * 252 + ((int)blockIdx.x >> 3);
  int q = sidx, gi = 0;
  while (q >= 64 * gi + 28) { q -= 64 * gi + 28; ++gi; }
  int I, J;
  if (q < 64 * gi) {
    int gj = q >> 6, r = q & 63;
    I = gi * 8 + (r >> 3);
    J = gj * 8 + (r & 7);
  } else {
    int dq = q - 64 * gi;
    int il = 1;
    while (il * (il + 1) / 2 <= dq) ++il;
    I = gi * 8 + il;
    J = gi * 8 + (dq - il * (il - 1) / 2);
  }

  const bf16_t* baseA = q2t + (size_t)(J * DIM) * BATCH;   // tensor 0 panels
  const bf16_t* baseB = q2t + (size_t)(I * DIM) * BATCH;

  const int tid  = threadIdx.x;
  const int lane = tid & 63, w = tid >> 6;
  const int wm = w & 1, wn = w >> 1;

  // staging: lane stores global chunk cc at LDS slot (tid&7) (XOR swizzle)
  const int rr = tid >> 3;
  const int cc = (tid & 7) ^ (rr & 7);
  const int goff = rr * BATCH + cc * 8;
  char* Lb = (char*)L;
  const int stA = w * 1024;            // + r*4096 (+ lane*16 implicit)
  const int stB = 16384 + w * 1024;

  // reader pointers (within buffer 0); row stride BK=64 el = 128 B
  const int l15 = lane & 15, qtr = lane >> 4;
  const int swz0 = ((qtr)     ^ (l15 & 7)) * 8;
  const int swz1 = ((4 + qtr) ^ (l15 & 7)) * 8;
  const bf16_t* Ap0 = L + (wm * 64 + l15) * BK + swz0;
  const bf16_t* Ap1 = L + (wm * 64 + l15) * BK + swz1;
  const bf16_t* Bp0 = L + 8192 + (wn * 64 + l15) * BK + swz0;
  const bf16_t* Bp1 = L + 8192 + (wn * 64 + l15) * BK + swz1;

  f32x4 acc[4][4];
#pragma unroll
  for (int i = 0; i < 4; ++i)
#pragma unroll
    for (int j = 0; j < 4; ++j) acc[i][j] = (f32x4){0.f, 0.f, 0.f, 0.f};

  float S0 = 0.f, S1 = 0.f;

  // prologue: stage chunk 0 into buf0
  {
    const bf16_t* gA = baseA + goff;
    const bf16_t* gB = baseB + goff;
#pragma unroll
    for (int r = 0; r < 4; ++r) {
      ld_lds16(gA + r * (32 * BATCH), Lb + r * 4096 + stA);
      ld_lds16(gB + r * (32 * BATCH), Lb + r * 4096 + stB);
    }
  }

  for (int m = 0; m < 16; ++m) {
    if (m < 15) {                       // prefetch chunk m+1 into buf (m+1)&1
      const int mi = m + 1;
      const int bb = (mi & 1) << 15;    // byte offset of buffer
      const bf16_t* gA = baseA + (size_t)(mi >> 3) * TSTR + (mi & 7) * BK + goff;
      const bf16_t* gB = baseB + (size_t)(mi >> 3) * TSTR + (mi & 7) * BK + goff;
#pragma unroll
      for (int r = 0; r < 4; ++r) {
        ld_lds16(gA + r * (32 * BATCH), Lb + bb + r * 4096 + stA);
        ld_lds16(gB + r * (32 * BATCH), Lb + bb + r * 4096 + stB);
      }
      SYNC_VM8();                       // oldest 8 (= chunk m) have landed
    } else {
      SYNC_VM0();
    }

    const int be = (m & 1) << 14;       // element offset of buffer
    bf16x8 a[4], b[4];
#pragma unroll
    for (int i = 0; i < 4; ++i) {
      a[i] = *(const bf16x8*)(Ap0 + be + i * (16 * BK));
      b[i] = *(const bf16x8*)(Bp0 + be + i * (16 * BK));
    }
#pragma unroll
    for (int i = 0; i < 4; ++i)
#pragma unroll
      for (int j = 0; j < 4; ++j)
        acc[i][j] = __builtin_amdgcn_mfma_f32_16x16x32_bf16(a[i], b[j], acc[i][j], 0, 0, 0);
#pragma unroll
    for (int i = 0; i < 4; ++i) {
      a[i] = *(const bf16x8*)(Ap1 + be + i * (16 * BK));
      b[i] = *(const bf16x8*)(Bp1 + be + i * (16 * BK));
    }
#pragma unroll
    for (int i = 0; i < 4; ++i)
#pragma unroll
      for (int j = 0; j < 4; ++j)
        acc[i][j] = __builtin_amdgcn_mfma_f32_16x16x32_bf16(a[i], b[j], acc[i][j], 0, 0, 0);

    if (m == 7) {                       // harvest tensor 0, reset acc
#pragma unroll
      for (int i = 0; i < 4; ++i)
#pragma unroll
        for (int j = 0; j < 4; ++j) {
#pragma unroll
          for (int e = 0; e < 4; ++e) S0 += sqrtf(acc[i][j][e]);
          acc[i][j] = (f32x4){0.f, 0.f, 0.f, 0.f};
        }
    }

    SYNC_LGKM();                        // all reads of buf(m&1) done before
  }                                     // next iter's prefetch overwrites it

  // harvest tensor 1
#pragma unroll
  for (int i = 0; i < 4; ++i)
#pragma unroll
    for (int j = 0; j < 4; ++j)
#pragma unroll
      for (int e = 0; e < 4; ++e) S1 += sqrtf(acc[i][j][e]);

  float local = S0 + S1;
#pragma unroll
  for (int off = 1; off < 64; off <<= 1) local += __shfl_xor(local, off);
  float* fred = (float*)L;              // LDS free after final barrier
  if (lane == 0) fred[w] = local;
  __syncthreads();
  if (tid == 0) Spart[blockIdx.x] = fred[0] + fred[1] + fred[2] + fred[3];
}

// ---------------------------------------------------------------------------
// Kernel 3: reduce partials and combine.
// P[0..1023] = dot partials, P[1024..3039] = S partials (both tensors, J<I).
// loss = -dot/(B*N_C) - S/((N_C^2-N_C)*sqrt(B))
// ---------------------------------------------------------------------------
__global__ __launch_bounds__(256) void finalize_kernel(
    const float* __restrict__ P, float* __restrict__ out) {
  __shared__ float rd[8];
  const int tid = threadIdx.x;
  float d = 0.f, s = 0.f;
  for (int i = tid; i < 1024; i += 256) d += P[i];
  for (int i = tid; i < NPAIR; i += 256) s += P[1024 + i];
#pragma unroll
  for (int off = 1; off < 64; off <<= 1) { d += __shfl_xor(d, off); s += __shfl_xor(s, off); }
  const int w = tid >> 6;
  if ((tid & 63) == 0) { rd[w] = d; rd[4 + w] = s; }
  __syncthreads();
  if (tid == 0) {
    float dt = rd[0] + rd[1] + rd[2] + rd[3];
    float st = rd[4] + rd[5] + rd[6] + rd[7];
    out[0] = -dt / 32768.0f - st / (4032.0f * 22.62741699796952f);
  }
}

extern "C" void kernel_launch(void* const* d_in, const int* in_sizes, int n_in,
                              void* d_out, int out_size, void* d_ws, size_t ws_size,
                              hipStream_t stream) {
  const float* emb = (const float*)d_in[0];
  float* out = (float*)d_out;
  float* P = (float*)d_ws;                                     // 3040 partials
  unsigned short* q2t = (unsigned short*)((char*)d_ws + 16384);  // 2x8192x512 bf16

  softmax_q2_kernel<<<dim3(16, 64), 256, 0, stream>>>(emb, q2t, P);
  gram_sqrt_kernel<<<dim3(NPAIR), 256, 0, stream>>>((const bf16_t*)q2t, P + 1024);
  finalize_kernel<<<1, 256, 0, stream>>>(P, out);
}

// Round 4
// 137.209 us; speedup vs baseline: 1.4862x; 1.1698x over previous
//
#include <hip/hip_runtime.h>
#include <cstdint>
#include <cstddef>

// Problem constants
#define NCLUS 64
#define DIM   128
#define BATCH 512              // K of the Gram reduction
#define QCOLS 8192             // NCLUS*DIM
#define NPAIR 2016             // 64*63/2
#define TSTRB (QCOLS * BATCH)  // BYTES per tensor in fp8 (4,194,304)
#define FP8SCALE 256.0f        // q^2 * 256 -> e4m3 (max 256 < 448, no clip)

typedef float f32x4 __attribute__((ext_vector_type(4)));

__device__ __forceinline__ void ld_lds16(const void* g, void* l) {
  __builtin_amdgcn_global_load_lds(
      (__attribute__((address_space(1))) void*)g,
      (__attribute__((address_space(3))) void*)l, 16, 0, 0);
}

// asm volatile + memory clobber = compiler fence: prefetch can't sink below.
#define SYNC_VM4()  asm volatile("s_waitcnt vmcnt(4)\n\ts_barrier" ::: "memory")
#define SYNC_VM0()  asm volatile("s_waitcnt vmcnt(0)\n\ts_barrier" ::: "memory")
#define SYNC_LGKM() asm volatile("s_waitcnt lgkmcnt(0)\n\ts_barrier" ::: "memory")

// ---------------------------------------------------------------------------
// Kernel 1: softmax over D=128, q^2*256 -> fp8 e4m3, transposed write
// q2t[t][c*128+d][b] (row = 512 B, K-contiguous). Block (bq, c): 32 b x 2
// tensors, 8 threads/row. T padded to 130 u16 (fp8 byte in low byte):
// write-out reads are conflict-free, writes 2-way (free).
// ---------------------------------------------------------------------------
__global__ __launch_bounds__(256) void softmax_q2_kernel(
    const float* __restrict__ emb, uint8_t* __restrict__ q2t,
    float* __restrict__ dotPart) {
  __shared__ unsigned short T[2][32][130];   // 16.25 KB
  __shared__ float red[4];
  const int c  = blockIdx.y;
  const int bq = blockIdx.x;
  const int tid = threadIdx.x;
  const int w = tid >> 6, lane = tid & 63;
  const int bl = tid >> 3;                   // 0..31
  const int part = tid & 7;                  // d-range part*16..+16
  const int b = bq * 32 + bl;

  float qa[16];
  float dot = 0.f;
#pragma unroll
  for (int t = 0; t < 2; ++t) {
    const float4* rp = (const float4*)(emb + ((size_t)(t * BATCH + b) * QCOLS +
                                              (size_t)c * DIM + part * 16));
    float f[16];
#pragma unroll
    for (int u = 0; u < 4; ++u) {
      float4 v = rp[u];
      f[4*u] = v.x; f[4*u+1] = v.y; f[4*u+2] = v.z; f[4*u+3] = v.w;
    }
    float mx = f[0];
#pragma unroll
    for (int j = 1; j < 16; ++j) mx = fmaxf(mx, f[j]);
#pragma unroll
    for (int off = 1; off < 8; off <<= 1) mx = fmaxf(mx, __shfl_xor(mx, off));
    float s = 0.f;
#pragma unroll
    for (int j = 0; j < 16; ++j) { f[j] = __expf(f[j] - mx); s += f[j]; }
#pragma unroll
    for (int off = 1; off < 8; off <<= 1) s += __shfl_xor(s, off);
    float inv = 1.0f / s;
    uint32_t* Tu = (uint32_t*)&T[t][bl][part * 16];
#pragma unroll
    for (int j = 0; j < 16; j += 2) {
      float q0 = f[j] * inv, q1 = f[j + 1] * inv;
      if (t == 0) { qa[j] = q0; qa[j + 1] = q1; }
      else        { dot += qa[j] * q0 + qa[j + 1] * q1; }
      // pack 2 fp8(e4m3) of q^2*256 into bytes 0 and 2 of a u32 (u16 slots)
      int pk2 = __builtin_amdgcn_cvt_pk_fp8_f32(q0 * q0 * FP8SCALE,
                                                q1 * q1 * FP8SCALE, 0, false);
      Tu[j >> 1] = ((uint32_t)pk2 & 0xFFu) | (((uint32_t)pk2 & 0xFF00u) << 8);
    }
  }
  __syncthreads();

  // transposed write-out: 1024 chunks of 8 B (8 consecutive b for one (t,d))
#pragma unroll
  for (int it = 0; it < 4; ++it) {
    int ch = it * 256 + tid;               // 0..1023
    int t = ch >> 9, d = (ch >> 2) & 127, b8 = ch & 3;
    uint32_t lo = 0, hi = 0;
#pragma unroll
    for (int r = 0; r < 4; ++r)
      lo |= ((uint32_t)T[t][b8 * 8 + r][d] & 0xFFu) << (8 * r);
#pragma unroll
    for (int r = 0; r < 4; ++r)
      hi |= ((uint32_t)T[t][b8 * 8 + 4 + r][d] & 0xFFu) << (8 * r);
    size_t off = (size_t)t * TSTRB + (size_t)(c * DIM + d) * BATCH +
                 (size_t)bq * 32 + b8 * 8;
    uint2 o; o.x = lo; o.y = hi;
    *(uint2*)(q2t + off) = o;
  }

#pragma unroll
  for (int off = 1; off < 64; off <<= 1) dot += __shfl_xor(dot, off);
  if (lane == 0) red[w] = dot;
  __syncthreads();
  if (tid == 0) dotPart[blockIdx.y * 16 + blockIdx.x] = red[0] + red[1] + red[2] + red[3];
}

// ---------------------------------------------------------------------------
// Kernel 2: fp8 Gram tile (J,I), J<I, both tensors per block (16 chunks of
// K-bytes=64), 128x128 tile, 4 waves (2x2), 16x16x32 fp8 MFMA, double-buffered
// LDS (2 x 16 KB -> 4 blocks/CU) with one-chunk-ahead global_load_lds prefetch
// (s_waitcnt vmcnt(4)). Per-row chunk-rotation swizzle keeps ds_read_b64 at
// 2-way (free) aliasing. XCD supertile pair ordering. Partial S -> store.
// ---------------------------------------------------------------------------
__global__ __launch_bounds__(256, 4) void gram_sqrt_kernel(
    const uint8_t* __restrict__ q2t, float* __restrict__ Spart) {
  __shared__ uint8_t L[32768 + 16];  // buf0 A@0 B@8192, buf1 A@16384 B@24576

  // ---- pair decode: XCD partition + 8x8 supertile order ----
  int sidx = ((int)blockIdx.x & 7) * 252 + ((int)blockIdx.x >> 3);
  int q = sidx, gi = 0;
  while (q >= 64 * gi + 28) { q -= 64 * gi + 28; ++gi; }
  int I, J;
  if (q < 64 * gi) {
    int gj = q >> 6, r = q & 63;
    I = gi * 8 + (r >> 3);
    J = gj * 8 + (r & 7);
  } else {
    int dq = q - 64 * gi;
    int il = 1;
    while (il * (il + 1) / 2 <= dq) ++il;
    I = gi * 8 + il;
    J = gi * 8 + (dq - il * (il - 1) / 2);
  }

  const uint8_t* baseA = q2t + (size_t)J * (DIM * BATCH);  // 64 KB panels
  const uint8_t* baseB = q2t + (size_t)I * (DIM * BATCH);

  const int tid  = threadIdx.x;
  const int lane = tid & 63, w = tid >> 6;
  const int wm = w & 1, wn = w >> 1;

  // --- staging source offsets (2 rounds x 256 slots of 16 B per operand) ---
  // slot t: row = t>>2, sl = t&3 holds content chunk c16 = (sl - ((row>>1)&3))&3
  const int t0 = tid, t1 = 256 + tid;
  const int r0s = t0 >> 2, r1s = t1 >> 2;
  const int c0s = ((t0 & 3) - ((r0s >> 1) & 3)) & 3;
  const int c1s = ((t1 & 3) - ((r1s >> 1) & 3)) & 3;
  const size_t g0 = (size_t)r0s * BATCH + c0s * 16;
  const size_t g1 = (size_t)r1s * BATCH + c1s * 16;
  uint8_t* Lb = L;
  const int ldsw = w * 1024;   // wave-uniform dest base within a 4 KB round

  // --- reader offsets: frag (i, kstep s): row = w?*64+i*16+l15, 8 B at
  // swizzled chunk ((2s + (qtr>>1) + g)&3)*16 + (qtr&1)*8, g = (l15>>1)&3 ---
  const int l15 = lane & 15, qtr = lane >> 4;
  const int gsw = (l15 >> 1) & 3;
  const int c16_0 = (((qtr >> 1)) + gsw) & 3;
  const int c16_1 = ((2 + (qtr >> 1)) + gsw) & 3;
  const int Aoff0 = wm * 4096 + l15 * 64 + (qtr & 1) * 8 + c16_0 * 16;
  const int Aoff1 = wm * 4096 + l15 * 64 + (qtr & 1) * 8 + c16_1 * 16;
  const int Boff0 = 8192 + wn * 4096 + l15 * 64 + (qtr & 1) * 8 + c16_0 * 16;
  const int Boff1 = 8192 + wn * 4096 + l15 * 64 + (qtr & 1) * 8 + c16_1 * 16;

  f32x4 acc[4][4];
#pragma unroll
  for (int i = 0; i < 4; ++i)
#pragma unroll
    for (int j = 0; j < 4; ++j) acc[i][j] = (f32x4){0.f, 0.f, 0.f, 0.f};

  float S0 = 0.f, S1 = 0.f;

  // prologue: stage chunk 0 into buf0 (4 loads)
  {
    ld_lds16(baseA + g0, Lb + ldsw);
    ld_lds16(baseA + g1, Lb + 4096 + ldsw);
    ld_lds16(baseB + g0, Lb + 8192 + ldsw);
    ld_lds16(baseB + g1, Lb + 12288 + ldsw);
  }

  for (int m = 0; m < 16; ++m) {
    if (m < 15) {                       // prefetch chunk m+1 into buf (m+1)&1
      const int mi = m + 1;
      const int bb = (mi & 1) << 14;    // 16384-byte buffer stride
      const size_t ck = (size_t)(mi >> 3) * TSTRB + (size_t)(mi & 7) * 64;
      ld_lds16(baseA + ck + g0, Lb + bb + ldsw);
      ld_lds16(baseA + ck + g1, Lb + bb + 4096 + ldsw);
      ld_lds16(baseB + ck + g0, Lb + bb + 8192 + ldsw);
      ld_lds16(baseB + ck + g1, Lb + bb + 12288 + ldsw);
      SYNC_VM4();                       // oldest 4 (= chunk m) have landed
    } else {
      SYNC_VM0();
    }

    const int be = (m & 1) << 14;
    long a[4], b[4];
#pragma unroll
    for (int i = 0; i < 4; ++i) {       // kstep 0
      a[i] = *(const long*)(Lb + be + Aoff0 + i * 1024);
      b[i] = *(const long*)(Lb + be + Boff0 + i * 1024);
    }
#pragma unroll
    for (int i = 0; i < 4; ++i)
#pragma unroll
      for (int j = 0; j < 4; ++j)
        acc[i][j] = __builtin_amdgcn_mfma_f32_16x16x32_fp8_fp8(a[i], b[j], acc[i][j], 0, 0, 0);
#pragma unroll
    for (int i = 0; i < 4; ++i) {       // kstep 1
      a[i] = *(const long*)(Lb + be + Aoff1 + i * 1024);
      b[i] = *(const long*)(Lb + be + Boff1 + i * 1024);
    }
#pragma unroll
    for (int i = 0; i < 4; ++i)
#pragma unroll
      for (int j = 0; j < 4; ++j)
        acc[i][j] = __builtin_amdgcn_mfma_f32_16x16x32_fp8_fp8(a[i], b[j], acc[i][j], 0, 0, 0);

    if (m == 7) {                       // harvest tensor 0, reset acc
#pragma unroll
      for (int i = 0; i < 4; ++i)
#pragma unroll
        for (int j = 0; j < 4; ++j) {
#pragma unroll
          for (int e = 0; e < 4; ++e) S0 += sqrtf(acc[i][j][e]);
          acc[i][j] = (f32x4){0.f, 0.f, 0.f, 0.f};
        }
    }

    SYNC_LGKM();                        // buf(m&1) reads done before overwrite
  }

  // harvest tensor 1
#pragma unroll
  for (int i = 0; i < 4; ++i)
#pragma unroll
    for (int j = 0; j < 4; ++j)
#pragma unroll
      for (int e = 0; e < 4; ++e) S1 += sqrtf(acc[i][j][e]);

  // G was scaled by 256*256 -> sqrt scaled by 256
  float local = (S0 + S1) * (1.0f / 256.0f);
#pragma unroll
  for (int off = 1; off < 64; off <<= 1) local += __shfl_xor(local, off);
  float* fred = (float*)(L + 32768);
  if (lane == 0) fred[w] = local;
  __syncthreads();
  if (tid == 0) Spart[blockIdx.x] = fred[0] + fred[1] + fred[2] + fred[3];
}

// ---------------------------------------------------------------------------
// Kernel 3: reduce partials and combine.
// P[0..1023] = dot partials, P[1024..3039] = S partials.
// loss = -dot/(B*N_C) - S/((N_C^2-N_C)*sqrt(B))
// ---------------------------------------------------------------------------
__global__ __launch_bounds__(256) void finalize_kernel(
    const float* __restrict__ P, float* __restrict__ out) {
  __shared__ float rd[8];
  const int tid = threadIdx.x;
  float d = 0.f, s = 0.f;
  for (int i = tid; i < 1024; i += 256) d += P[i];
  for (int i = tid; i < NPAIR; i += 256) s += P[1024 + i];
#pragma unroll
  for (int off = 1; off < 64; off <<= 1) { d += __shfl_xor(d, off); s += __shfl_xor(s, off); }
  const int w = tid >> 6;
  if ((tid & 63) == 0) { rd[w] = d; rd[4 + w] = s; }
  __syncthreads();
  if (tid == 0) {
    float dt = rd[0] + rd[1] + rd[2] + rd[3];
    float st = rd[4] + rd[5] + rd[6] + rd[7];
    out[0] = -dt / 32768.0f - st / (4032.0f * 22.62741699796952f);
  }
}

extern "C" void kernel_launch(void* const* d_in, const int* in_sizes, int n_in,
                              void* d_out, int out_size, void* d_ws, size_t ws_size,
                              hipStream_t stream) {
  const float* emb = (const float*)d_in[0];
  float* out = (float*)d_out;
  float* P = (float*)d_ws;                                 // 3040 partials
  uint8_t* q2t = (uint8_t*)d_ws + 16384;                   // 2 x 8192 x 512 fp8

  softmax_q2_kernel<<<dim3(16, 64), 256, 0, stream>>>(emb, q2t, P);
  gram_sqrt_kernel<<<dim3(NPAIR), 256, 0, stream>>>(q2t, P + 1024);
  finalize_kernel<<<1, 256, 0, stream>>>(P, out);
}

// Round 5
// 133.927 us; speedup vs baseline: 1.5226x; 1.0245x over previous
//
#include <hip/hip_runtime.h>
#include <cstdint>
#include <cstddef>

// Problem constants
#define NCLUS 64
#define DIM   128
#define BATCH 512              // K of the Gram reduction (bytes per fp8 row)
#define QCOLS 8192             // NCLUS*DIM
#define NPAIR 2016             // 64*63/2
#define TSTRB (QCOLS * BATCH)  // BYTES per tensor in fp8 (4,194,304)
#define FP8SCALE 256.0f        // q^2 * 256 -> e4m3 (max 256 < 448, no clip)

typedef float f32x4 __attribute__((ext_vector_type(4)));
typedef long  lx2  __attribute__((ext_vector_type(2)));

// q2t layout: row (t, c*128+d) of 512 bytes over b. Within each 64-byte
// k-chunk, 8-byte units are PERMUTED: global unit u (=(b&63)>>3) stored at
// position p=(u&3)*2+(u>>2). So the 16-B chunk at slot q holds units
// [q | 4+q] = exactly ksteps 0,1 for MFMA-quarter q -> one ds_read_b128
// feeds both ksteps of a lane.

__device__ __forceinline__ void ld_lds16(const void* g, void* l) {
  __builtin_amdgcn_global_load_lds(
      (__attribute__((address_space(1))) void*)g,
      (__attribute__((address_space(3))) void*)l, 16, 0, 0);
}

#define SYNC_VM4()  asm volatile("s_waitcnt vmcnt(4)\n\ts_barrier" ::: "memory")
#define SYNC_VM0()  asm volatile("s_waitcnt vmcnt(0)\n\ts_barrier" ::: "memory")
#define SYNC_LGKM() asm volatile("s_waitcnt lgkmcnt(0)\n\ts_barrier" ::: "memory")

// ---------------------------------------------------------------------------
// Kernel 1: softmax over D=128, q^2*256 -> fp8 e4m3, permuted-transposed write.
// Block (bq8 in 0..7, c in 0..63): 64 b's x 2 tensors; 4 threads per row
// (32 d each). Every 64-B line of q2t is written ENTIRELY by this block
// (full-line dirty evictions -> no write amplification).
// ---------------------------------------------------------------------------
__global__ __launch_bounds__(256) void softmax_q2_kernel(
    const float* __restrict__ emb, uint8_t* __restrict__ q2t,
    float* __restrict__ dotPart) {
  __shared__ unsigned short T[2][64][130];   // fp8 byte in low byte; 33,280 B
  __shared__ float red[4];
  const int c   = blockIdx.y;
  const int bq8 = blockIdx.x;
  const int tid = threadIdx.x;
  const int w = tid >> 6, lane = tid & 63;
  const int bl = tid >> 2;                   // 0..63 local b
  const int qd = tid & 3;                    // d-range qd*32..+32
  const int b = bq8 * 64 + bl;

  float qa[32];
  float dot = 0.f;
#pragma unroll
  for (int t = 0; t < 2; ++t) {
    const float4* rp = (const float4*)(emb + ((size_t)(t * BATCH + b) * QCOLS +
                                              (size_t)c * DIM + qd * 32));
    float f[32];
#pragma unroll
    for (int u = 0; u < 8; ++u) {
      float4 v = rp[u];
      f[4*u] = v.x; f[4*u+1] = v.y; f[4*u+2] = v.z; f[4*u+3] = v.w;
    }
    float mx = f[0];
#pragma unroll
    for (int j = 1; j < 32; ++j) mx = fmaxf(mx, f[j]);
    mx = fmaxf(mx, __shfl_xor(mx, 1));
    mx = fmaxf(mx, __shfl_xor(mx, 2));
    float s = 0.f;
#pragma unroll
    for (int j = 0; j < 32; ++j) { f[j] = __expf(f[j] - mx); s += f[j]; }
    s += __shfl_xor(s, 1);
    s += __shfl_xor(s, 2);
    float inv = 1.0f / s;
    uint32_t* Tu = (uint32_t*)&T[t][bl][qd * 32];
#pragma unroll
    for (int j = 0; j < 32; j += 2) {
      float q0 = f[j] * inv, q1 = f[j + 1] * inv;
      if (t == 0) { qa[j] = q0; qa[j + 1] = q1; }
      else        { dot += qa[j] * q0 + qa[j + 1] * q1; }
      int pk2 = __builtin_amdgcn_cvt_pk_fp8_f32(q0 * q0 * FP8SCALE,
                                                q1 * q1 * FP8SCALE, 0, false);
      Tu[j >> 1] = ((uint32_t)pk2 & 0xFFu) | (((uint32_t)pk2 & 0xFF00u) << 8);
    }
  }
  __syncthreads();

  // write-out: 1024 chunks of 16 B; chunk (t,d,b16) = [unit b16 | unit 4+b16]
  // (permuted order). 4 consecutive lanes complete one 64-B line.
#pragma unroll
  for (int it = 0; it < 4; ++it) {
    int ch = it * 256 + tid;               // 0..1023
    int t = ch >> 9, d = (ch >> 2) & 127, b16 = ch & 3;
    uint32_t w0 = 0, w1 = 0, w2 = 0, w3 = 0;
#pragma unroll
    for (int r = 0; r < 4; ++r) {
      w0 |= ((uint32_t)T[t][b16 * 8 + r][d] & 0xFFu) << (8 * r);
      w1 |= ((uint32_t)T[t][b16 * 8 + 4 + r][d] & 0xFFu) << (8 * r);
      w2 |= ((uint32_t)T[t][32 + b16 * 8 + r][d] & 0xFFu) << (8 * r);
      w3 |= ((uint32_t)T[t][32 + b16 * 8 + 4 + r][d] & 0xFFu) << (8 * r);
    }
    size_t off = (size_t)t * TSTRB + (size_t)(c * DIM + d) * BATCH +
                 (size_t)bq8 * 64 + b16 * 16;
    uint4 o; o.x = w0; o.y = w1; o.z = w2; o.w = w3;
    *(uint4*)(q2t + off) = o;
  }

#pragma unroll
  for (int off = 1; off < 64; off <<= 1) dot += __shfl_xor(dot, off);
  if (lane == 0) red[w] = dot;
  __syncthreads();
  if (tid == 0) dotPart[blockIdx.y * 8 + blockIdx.x] = red[0] + red[1] + red[2] + red[3];
}

// ---------------------------------------------------------------------------
// Kernel 2: fp8 Gram tile (J,I), J<I, both tensors per block (16 chunks of 64
// K-bytes), 128x128 tile, 4 waves (2x2), 16x16x32 fp8 MFMA, double-buffered
// LDS (2 x 16 KB, 4 blocks/CU) with one-chunk-ahead prefetch (vmcnt(4)).
// Reader: ONE ds_read_b128 per frag-row = both ksteps (permuted layout);
// slot%8 injective over 8-lane groups -> conflict-free (R2/R3 mechanism).
// ---------------------------------------------------------------------------
__global__ __launch_bounds__(256, 4) void gram_sqrt_kernel(
    const uint8_t* __restrict__ q2t, float* __restrict__ Spart) {
  __shared__ uint8_t L[32768 + 16];  // buf0 A@0 B@8192, buf1 A@16384 B@24576

  // ---- pair decode: XCD partition + 8x8 supertile order ----
  int sidx = ((int)blockIdx.x & 7) * 252 + ((int)blockIdx.x >> 3);
  int q = sidx, gi = 0;
  while (q >= 64 * gi + 28) { q -= 64 * gi + 28; ++gi; }
  int I, J;
  if (q < 64 * gi) {
    int gj = q >> 6, r = q & 63;
    I = gi * 8 + (r >> 3);
    J = gj * 8 + (r & 7);
  } else {
    int dq = q - 64 * gi;
    int il = 1;
    while (il * (il + 1) / 2 <= dq) ++il;
    I = gi * 8 + il;
    J = gi * 8 + (dq - il * (il - 1) / 2);
  }

  const uint8_t* baseA = q2t + (size_t)J * (DIM * BATCH);  // 64 KB panels
  const uint8_t* baseB = q2t + (size_t)I * (DIM * BATCH);

  const int tid  = threadIdx.x;
  const int lane = tid & 63, w = tid >> 6;
  const int wm = w & 1, wn = w >> 1;

  // staging: slot t holds (row r=t>>2, phys p=t&3) <- global chunk (p-(r>>1))&3
  const int t0 = tid, t1 = 256 + tid;
  const int r0s = t0 >> 2, r1s = t1 >> 2;
  const int c0s = ((t0 & 3) - ((r0s >> 1) & 3)) & 3;
  const int c1s = ((t1 & 3) - ((r1s >> 1) & 3)) & 3;
  const size_t g0 = (size_t)r0s * BATCH + c0s * 16;
  const size_t g1 = (size_t)r1s * BATCH + c1s * 16;
  uint8_t* Lb = L;
  const int ldsw = w * 1024;   // wave-uniform dest base within a 4 KB round

  // reader: frag-row r = wm*64+i*16+l15, phys slot (qtr+(r>>1))&3 =
  // (qtr+(l15>>1))&3 (i*8, wm*32 vanish mod 4) -> 16 B = ksteps 0,1
  const int l15 = lane & 15, qtr = lane >> 4;
  const int sig = ((qtr + (l15 >> 1)) & 3) * 16;
  const int ApO = wm * 4096 + l15 * 64 + sig;
  const int BpO = 8192 + wn * 4096 + l15 * 64 + sig;

  f32x4 acc[4][4];
#pragma unroll
  for (int i = 0; i < 4; ++i)
#pragma unroll
    for (int j = 0; j < 4; ++j) acc[i][j] = (f32x4){0.f, 0.f, 0.f, 0.f};

  float S0 = 0.f, S1 = 0.f;

  // prologue: stage chunk 0 into buf0
  ld_lds16(baseA + g0, Lb + ldsw);
  ld_lds16(baseA + g1, Lb + 4096 + ldsw);
  ld_lds16(baseB + g0, Lb + 8192 + ldsw);
  ld_lds16(baseB + g1, Lb + 12288 + ldsw);

  for (int m = 0; m < 16; ++m) {
    if (m < 15) {                       // prefetch chunk m+1 into buf (m+1)&1
      const int mi = m + 1;
      const int bb = (mi & 1) << 14;
      const size_t ck = (size_t)(mi >> 3) * TSTRB + (size_t)(mi & 7) * 64;
      ld_lds16(baseA + ck + g0, Lb + bb + ldsw);
      ld_lds16(baseA + ck + g1, Lb + bb + 4096 + ldsw);
      ld_lds16(baseB + ck + g0, Lb + bb + 8192 + ldsw);
      ld_lds16(baseB + ck + g1, Lb + bb + 12288 + ldsw);
      SYNC_VM4();                       // oldest 4 (= chunk m) have landed
    } else {
      SYNC_VM0();
    }

    const int be = (m & 1) << 14;
    lx2 a[4], b[4];
#pragma unroll
    for (int i = 0; i < 4; ++i) {       // one b128 per frag-row: both ksteps
      a[i] = *(const lx2*)(Lb + be + ApO + i * 1024);
      b[i] = *(const lx2*)(Lb + be + BpO + i * 1024);
    }
#pragma unroll
    for (int i = 0; i < 4; ++i)
#pragma unroll
      for (int j = 0; j < 4; ++j)
        acc[i][j] = __builtin_amdgcn_mfma_f32_16x16x32_fp8_fp8(a[i].x, b[j].x, acc[i][j], 0, 0, 0);
#pragma unroll
    for (int i = 0; i < 4; ++i)
#pragma unroll
      for (int j = 0; j < 4; ++j)
        acc[i][j] = __builtin_amdgcn_mfma_f32_16x16x32_fp8_fp8(a[i].y, b[j].y, acc[i][j], 0, 0, 0);

    if (m == 7) {                       // harvest tensor 0, reset acc
#pragma unroll
      for (int i = 0; i < 4; ++i)
#pragma unroll
        for (int j = 0; j < 4; ++j) {
#pragma unroll
          for (int e = 0; e < 4; ++e) S0 += sqrtf(acc[i][j][e]);
          acc[i][j] = (f32x4){0.f, 0.f, 0.f, 0.f};
        }
    }

    SYNC_LGKM();                        // buf(m&1) reads done before overwrite
  }

  // harvest tensor 1
#pragma unroll
  for (int i = 0; i < 4; ++i)
#pragma unroll
    for (int j = 0; j < 4; ++j)
#pragma unroll
      for (int e = 0; e < 4; ++e) S1 += sqrtf(acc[i][j][e]);

  // G was scaled by 256*256 -> sqrt scaled by 256
  float local = (S0 + S1) * (1.0f / 256.0f);
#pragma unroll
  for (int off = 1; off < 64; off <<= 1) local += __shfl_xor(local, off);
  float* fred = (float*)(L + 32768);
  if (lane == 0) fred[w] = local;
  __syncthreads();
  if (tid == 0) Spart[blockIdx.x] = fred[0] + fred[1] + fred[2] + fred[3];
}

// ---------------------------------------------------------------------------
// Kernel 3: reduce partials and combine.
// P[0..511] = dot partials, P[512..2527] = S partials.
// loss = -dot/(B*N_C) - S/((N_C^2-N_C)*sqrt(B))
// ---------------------------------------------------------------------------
__global__ __launch_bounds__(256) void finalize_kernel(
    const float* __restrict__ P, float* __restrict__ out) {
  __shared__ float rd[8];
  const int tid = threadIdx.x;
  float d = 0.f, s = 0.f;
  for (int i = tid; i < 512; i += 256) d += P[i];
  for (int i = tid; i < NPAIR; i += 256) s += P[512 + i];
#pragma unroll
  for (int off = 1; off < 64; off <<= 1) { d += __shfl_xor(d, off); s += __shfl_xor(s, off); }
  const int w = tid >> 6;
  if ((tid & 63) == 0) { rd[w] = d; rd[4 + w] = s; }
  __syncthreads();
  if (tid == 0) {
    float dt = rd[0] + rd[1] + rd[2] + rd[3];
    float st = rd[4] + rd[5] + rd[6] + rd[7];
    out[0] = -dt / 32768.0f - st / (4032.0f * 22.62741699796952f);
  }
}

extern "C" void kernel_launch(void* const* d_in, const int* in_sizes, int n_in,
                              void* d_out, int out_size, void* d_ws, size_t ws_size,
                              hipStream_t stream) {
  const float* emb = (const float*)d_in[0];
  float* out = (float*)d_out;
  float* P = (float*)d_ws;                                 // 2528 partials
  uint8_t* q2t = (uint8_t*)d_ws + 16384;                   // 2 x 8192 x 512 fp8

  softmax_q2_kernel<<<dim3(8, 64), 256, 0, stream>>>(emb, q2t, P);
  gram_sqrt_kernel<<<dim3(NPAIR), 256, 0, stream>>>(q2t, P + 512);
  finalize_kernel<<<1, 256, 0, stream>>>(P, out);
}